// Round 7
// baseline (2038.022 us; speedup 1.0000x reference)
//
#include <hip/hip_runtime.h>

typedef unsigned short u16;
typedef unsigned int u32;
typedef __attribute__((ext_vector_type(8))) short bf16x8;
typedef __attribute__((ext_vector_type(4))) float f32x4;

__device__ __forceinline__ u16 f2bf(float f) {
  u32 u = __float_as_uint(f);
  u += 0x7fffu + ((u >> 16) & 1u);
  return (u16)(u >> 16);
}
__device__ __forceinline__ float bf2f(short h) {
  return __uint_as_float(((u32)(u16)h) << 16);
}

// ---------------- convert x: f32 -> bf16 (straight) ----------------
__global__ __launch_bounds__(256) void k_cvt(const float* __restrict__ in, u16* __restrict__ out, int n) {
  int idx = (blockIdx.x * 256 + threadIdx.x) * 8;
  if (idx >= n) return;
  float4 a = *(const float4*)&in[idx];
  float4 b = *(const float4*)&in[idx + 4];
  union { u16 h[8]; uint4 v; } t;
  t.h[0] = f2bf(a.x); t.h[1] = f2bf(a.y); t.h[2] = f2bf(a.z); t.h[3] = f2bf(a.w);
  t.h[4] = f2bf(b.x); t.h[5] = f2bf(b.y); t.h[6] = f2bf(b.z); t.h[7] = f2bf(b.w);
  *(uint4*)&out[idx] = t.v;
}

// ---------------- transpose+convert: out[c][r] = bf16(in[r][c]) ----------------
__global__ __launch_bounds__(256) void k_tcvt(const float* __restrict__ in, u16* __restrict__ out, int R, int C) {
  __shared__ u16 T[64 * 72];
  int t = threadIdx.x;
  int r0 = blockIdx.y * 64, c0 = blockIdx.x * 64;
  for (int i = 0; i < 4; i++) {
    int cc = i * 256 + t; int r = cc >> 4; int s = cc & 15;
    float4 v = *(const float4*)&in[(size_t)(r0 + r) * C + c0 + s * 4];
    T[r * 72 + s * 4 + 0] = f2bf(v.x);
    T[r * 72 + s * 4 + 1] = f2bf(v.y);
    T[r * 72 + s * 4 + 2] = f2bf(v.z);
    T[r * 72 + s * 4 + 3] = f2bf(v.w);
  }
  __syncthreads();
  for (int i = 0; i < 2; i++) {
    int cc = i * 256 + t; int c = cc >> 3; int s2 = cc & 7;
    union { u16 h[8]; uint4 v; } tmp;
    for (int e = 0; e < 8; e++) tmp.h[e] = T[(s2 * 8 + e) * 72 + c];
    *(uint4*)&out[(size_t)(c0 + c) * R + r0 + s2 * 8] = tmp.v;
  }
}

// ---------------- transpose v-part of qkv into Vt[512][8192] ----------------
__global__ __launch_bounds__(256) void k_tv(const u16* __restrict__ qkv, u16* __restrict__ vt) {
  __shared__ u16 T[64 * 72];
  int t = threadIdx.x;
  int r0 = blockIdx.y * 64, d0 = blockIdx.x * 64;
  for (int i = 0; i < 2; i++) {
    int cc = i * 256 + t; int r = cc >> 3; int s = cc & 7;
    *(uint4*)&T[r * 72 + s * 8] = *(const uint4*)&qkv[(size_t)(r0 + r) * 1536 + 1024 + d0 + s * 8];
  }
  __syncthreads();
  for (int i = 0; i < 2; i++) {
    int cc = i * 256 + t; int d = cc >> 3; int s2 = cc & 7;
    union { u16 h[8]; uint4 v; } tmp;
    for (int e = 0; e < 8; e++) tmp.h[e] = T[(s2 * 8 + e) * 72 + d];
    *(uint4*)&vt[(size_t)(d0 + d) * 8192 + r0 + s2 * 8] = tmp.v;
  }
}

// ---------------- GEMM (m97 structure) ----------------
__global__ __launch_bounds__(256) void k_gemm(const u16* __restrict__ A, const u16* __restrict__ Bt,
                                              const float* __restrict__ bias,
                                              u16* __restrict__ Cb, float* __restrict__ Cf,
                                              int M, int N, int K) {
  __shared__ u16 As[128 * 64];
  __shared__ u16 Bs[128 * 64];
  const int t = threadIdx.x;
  const int l = t & 63, w = t >> 6;
  const int l16 = l & 15, g = l >> 4;
  const int m0 = blockIdx.y * 128, n0 = blockIdx.x * 128;
  const int wr = (w >> 1) * 64, wc = (w & 1) * 64;
  f32x4 acc[4][4] = {};
  for (int kk = 0; kk < K; kk += 64) {
    __syncthreads();
#pragma unroll
    for (int i = 0; i < 4; i++) {
      int c = i * 256 + t;
      int r = c >> 3, g2 = c & 7;
      int sg = g2 ^ (r & 7);
      __builtin_amdgcn_global_load_lds(
          (const __attribute__((address_space(1))) u32*)(A + (size_t)(m0 + r) * K + kk + sg * 8),
          (__attribute__((address_space(3))) u32*)&As[c * 8], 16, 0, 0);
      __builtin_amdgcn_global_load_lds(
          (const __attribute__((address_space(1))) u32*)(Bt + (size_t)(n0 + r) * K + kk + sg * 8),
          (__attribute__((address_space(3))) u32*)&Bs[c * 8], 16, 0, 0);
    }
    __syncthreads();
#pragma unroll
    for (int kh = 0; kh < 2; kh++) {
      bf16x8 a[4];
#pragma unroll
      for (int mi = 0; mi < 4; mi++) {
        int row = wr + 16 * mi + l16;
        int s = (kh * 4 + g) ^ (row & 7);
        a[mi] = *(const bf16x8*)&As[row * 64 + s * 8];
      }
#pragma unroll
      for (int ni = 0; ni < 4; ni++) {
        int row = wc + 16 * ni + l16;
        int s = (kh * 4 + g) ^ (row & 7);
        bf16x8 b = *(const bf16x8*)&Bs[row * 64 + s * 8];
#pragma unroll
        for (int mi = 0; mi < 4; mi++)
          acc[mi][ni] = __builtin_amdgcn_mfma_f32_16x16x32_bf16(a[mi], b, acc[mi][ni], 0, 0, 0);
      }
    }
  }
#pragma unroll
  for (int ni = 0; ni < 4; ni++) {
    int col = n0 + wc + 16 * ni + l16;
    float bv = bias[col];
#pragma unroll
    for (int mi = 0; mi < 4; mi++) {
      int row0 = m0 + wr + 16 * mi + 4 * g;
#pragma unroll
      for (int r = 0; r < 4; r++) {
        float v = acc[mi][ni][r] + bv;
        if (Cf) Cf[(size_t)(row0 + r) * N + col] = v;
        else    Cb[(size_t)(row0 + r) * N + col] = f2bf(v);
      }
    }
  }
}

// ---------------- flash v7: BQ=128, 4 waves x 32q x 512d, 1 wave/SIMD (512 VGPR cap) ----------------
// Same chunking/slots as v5: Gq=8, CT=32 tiles (1024 tok), 288 slots, nch(qb)=(qb>>3)+1,
// slot = (a+1)*(4a+b)+c with a=qb>>3, b=qb&7.
// Op layout per slot (65536 u16): [vw(0..7)][db2(0..15)][lane][8], vw = 2*w + qh, rows 16*vw+4g+r.
__global__ __launch_bounds__(256, 1) void k_flash7(const u16* __restrict__ qkv, const u16* __restrict__ vt,
                                                   u16* __restrict__ opA, u16* __restrict__ opB,
                                                   float* __restrict__ ml, int lgGq, int SPLIT) {
  __shared__ u16 Ks[2][32 * 512];   // [kv][d], 16B units XOR-swizzled by kv-row (2-way max on read)
  __shared__ u16 Vs[2][32 * 512];   // subtiled: unit U = (d>>4)*64 + (kv>>3)*16 + (d&15)
  __shared__ u16 Ps[4][2][16 * 40]; // per-wave, per-q-half P strip [16 q][32 kv], stride 40
  const int qb = blockIdx.y, c = blockIdx.x;
  const int Gq = 1 << lgGq;
  const int a = qb >> lgGq, b = qb & (Gq - 1);
  const int nch = a + 1;
  if (c >= nch) return;
  const int slot = (a + 1) * ((Gq >> 1) * a + b) + c;
  const int CT = Gq << 2;
  const int jlo = c * CT;
  const int jhi = min(jlo + CT, (qb + 1) * 4);
  const int t = threadIdx.x;
  const int l = t & 63, w = t >> 6;           // w = 0..3
  const int l16 = l & 15, g = l >> 4;
  const int q0 = qb * 128;
  const int wq = q0 + 32 * w;                 // wave's first q row
  const float scale = 0.044194173824159216f;  // 1/sqrt(512)

  auto stageK = [&](int jt, int buf) {
    const u16* src = qkv + (size_t)(jt * 32) * 1536 + 512;
#pragma unroll
    for (int i = 0; i < 8; i++) {
      int cc = i * 256 + t;                   // 16B unit 0..2047
      int r = cc >> 6, u = cc & 63;
      int su = (u & 56) | ((u & 7) ^ (r & 7));
      __builtin_amdgcn_global_load_lds(
          (const __attribute__((address_space(1))) u32*)(src + (size_t)r * 1536 + su * 8),
          (__attribute__((address_space(3))) u32*)&Ks[buf][cc * 8], 16, 0, 0);
    }
  };
  auto stageV = [&](int jt, int buf) {
    const int tok0 = jt * 32;
#pragma unroll
    for (int i = 0; i < 8; i++) {
      int cc = i * 256 + t;                   // unit U: tile=U>>6, u=(U>>4)&3, dl=U&15
      int tile = cc >> 6, u = (cc >> 4) & 3, dl = cc & 15;
      int d = tile * 16 + dl;
      __builtin_amdgcn_global_load_lds(
          (const __attribute__((address_space(1))) u32*)(vt + (size_t)d * 8192 + tok0 + u * 8),
          (__attribute__((address_space(3))) u32*)&Vs[buf][cc * 8], 16, 0, 0);
    }
  };

  // hoist Q: 2 q-halves x 16 k-slices (128 VGPR)
  bf16x8 qa0[16], qa1[16];
#pragma unroll
  for (int ks = 0; ks < 16; ks++) {
    qa0[ks] = *(const bf16x8*)&qkv[(size_t)(wq + l16) * 1536 + ks * 32 + g * 8];
    qa1[ks] = *(const bf16x8*)&qkv[(size_t)(wq + 16 + l16) * 1536 + ks * 32 + g * 8];
  }

  f32x4 acc0[32] = {}, acc1[32] = {};         // O rows wq+16*qh+4g+r, col 16db+l16
  float m0s[4], l0s[4], m1s[4], l1s[4];
#pragma unroll
  for (int r = 0; r < 4; r++) { m0s[r] = -1.0e30f; l0s[r] = 0.f; m1s[r] = -1.0e30f; l1s[r] = 0.f; }

  stageK(jlo, jlo & 1);
  stageV(jlo, jlo & 1);
  __syncthreads();

  for (int jt = jlo; jt < jhi; ++jt) {
    const int buf = jt & 1;
    const int tok0 = jt * 32;
    if (jt + 1 < jhi) { stageK(jt + 1, buf ^ 1); stageV(jt + 1, buf ^ 1); }

    // ---- QK^T: 32 rows x 32 cols per wave, K=512; each K B-frag feeds 2 MFMAs ----
    f32x4 S00 = {0.f,0.f,0.f,0.f}, S01 = {0.f,0.f,0.f,0.f};
    f32x4 S10 = {0.f,0.f,0.f,0.f}, S11 = {0.f,0.f,0.f,0.f};
#pragma unroll
    for (int ks = 0; ks < 16; ks++) {
      int u = 4 * ks + g;
      int su = (u & 56) | ((u & 7) ^ (l16 & 7));
      bf16x8 k0 = *(const bf16x8*)&Ks[buf][l16 * 512 + su * 8];
      int su1 = (u & 56) | ((u & 7) ^ ((16 + l16) & 7));
      bf16x8 k1 = *(const bf16x8*)&Ks[buf][(16 + l16) * 512 + su1 * 8];
      S00 = __builtin_amdgcn_mfma_f32_16x16x32_bf16(qa0[ks], k0, S00, 0, 0, 0);
      S01 = __builtin_amdgcn_mfma_f32_16x16x32_bf16(qa0[ks], k1, S01, 0, 0, 0);
      S10 = __builtin_amdgcn_mfma_f32_16x16x32_bf16(qa1[ks], k0, S10, 0, 0, 0);
      S11 = __builtin_amdgcn_mfma_f32_16x16x32_bf16(qa1[ks], k1, S11, 0, 0, 0);
    }
    // ---- scale + causal mask (wave-uniform skip when tile fully visible) ----
#pragma unroll
    for (int r = 0; r < 4; r++) { S00[r] *= scale; S01[r] *= scale; S10[r] *= scale; S11[r] *= scale; }
    if (tok0 + 31 > wq) {
      const int km0 = tok0 + l16, km1 = tok0 + 16 + l16;
      const int qp0 = wq + 4 * g, qp1 = wq + 16 + 4 * g;
#pragma unroll
      for (int r = 0; r < 4; r++) {
        if (km0 > qp0 + r) S00[r] = -1e10f;
        if (km1 > qp0 + r) S01[r] = -1e10f;
        if (km0 > qp1 + r) S10[r] = -1e10f;
        if (km1 > qp1 + r) S11[r] = -1e10f;
      }
    }
    // ---- wave-local online softmax, defer-max THR=6, both q-halves ----
    float pm0[4], pm1[4];
#pragma unroll
    for (int r = 0; r < 4; r++) {
      float v0 = fmaxf(S00[r], S01[r]);
      float v1 = fmaxf(S10[r], S11[r]);
#pragma unroll
      for (int off = 1; off < 16; off <<= 1) {
        v0 = fmaxf(v0, __shfl_xor(v0, off));
        v1 = fmaxf(v1, __shfl_xor(v1, off));
      }
      pm0[r] = v0; pm1[r] = v1;
    }
    float sc0[4] = {1.f,1.f,1.f,1.f}, sc1[4] = {1.f,1.f,1.f,1.f};
    int need = 0;
#pragma unroll
    for (int r = 0; r < 4; r++)
      need |= (pm0[r] > m0s[r] + 6.f) | (pm1[r] > m1s[r] + 6.f);
    if (__any(need)) {
#pragma unroll
      for (int r = 0; r < 4; r++) {
        float mn0 = fmaxf(m0s[r], pm0[r]);
        float mn1 = fmaxf(m1s[r], pm1[r]);
        sc0[r] = __expf(m0s[r] - mn0); m0s[r] = mn0;
        sc1[r] = __expf(m1s[r] - mn1); m1s[r] = mn1;
      }
#pragma unroll
      for (int db = 0; db < 32; db++)
#pragma unroll
        for (int r = 0; r < 4; r++) { acc0[db][r] *= sc0[r]; acc1[db][r] *= sc1[r]; }
    }
#pragma unroll
    for (int r = 0; r < 4; r++) {
      float p00 = __expf(S00[r] - m0s[r]);
      float p01 = __expf(S01[r] - m0s[r]);
      float p10 = __expf(S10[r] - m1s[r]);
      float p11 = __expf(S11[r] - m1s[r]);
      Ps[w][0][(4 * g + r) * 40 + l16] = f2bf(p00);
      Ps[w][0][(4 * g + r) * 40 + 16 + l16] = f2bf(p01);
      Ps[w][1][(4 * g + r) * 40 + l16] = f2bf(p10);
      Ps[w][1][(4 * g + r) * 40 + 16 + l16] = f2bf(p11);
      float s0 = p00 + p01, s1 = p10 + p11;
#pragma unroll
      for (int off = 1; off < 16; off <<= 1) {
        s0 += __shfl_xor(s0, off);
        s1 += __shfl_xor(s1, off);
      }
      l0s[r] = l0s[r] * sc0[r] + s0;
      l1s[r] = l1s[r] * sc1[r] + s1;
    }
    // ---- PV: O[32x512] += P[32x32] @ V[32x512]; each V B-frag feeds 2 MFMAs ----
    bf16x8 pa0 = *(const bf16x8*)&Ps[w][0][l16 * 40 + g * 8];
    bf16x8 pa1 = *(const bf16x8*)&Ps[w][1][l16 * 40 + g * 8];
#pragma unroll
    for (int db = 0; db < 32; db++) {
      bf16x8 vb = *(const bf16x8*)&Vs[buf][db * 512 + g * 128 + l16 * 8];
      acc0[db] = __builtin_amdgcn_mfma_f32_16x16x32_bf16(pa0, vb, acc0[db], 0, 0, 0);
      acc1[db] = __builtin_amdgcn_mfma_f32_16x16x32_bf16(pa1, vb, acc1[db], 0, 0, 0);
    }
    __syncthreads();   // drains vmcnt (prefetch done) + protects dbuf + Ps
  }

  // ---- epilogue: vectorized unnormalized partials + (m,l) ----
  u16* op = (slot < SPLIT) ? (opA + (size_t)slot * 65536)
                           : (opB + (size_t)(slot - SPLIT) * 65536);
  uint4* opw = (uint4*)op;
#pragma unroll
  for (int db2 = 0; db2 < 16; db2++) {
    union { u16 h[8]; uint4 v; } p0, p1;
#pragma unroll
    for (int j = 0; j < 8; j++) {
      p0.h[j] = f2bf(acc0[2 * db2 + (j >> 2)][j & 3]);
      p1.h[j] = f2bf(acc1[2 * db2 + (j >> 2)][j & 3]);
    }
    opw[((2 * w + 0) * 16 + db2) * 64 + l] = p0.v;
    opw[((2 * w + 1) * 16 + db2) * 64 + l] = p1.v;
  }
  if (l16 == 0) {
#pragma unroll
    for (int r = 0; r < 4; r++) {
      int r0 = 32 * w + 4 * g + r;
      ml[slot * 256 + r0 * 2 + 0] = m0s[r];
      ml[slot * 256 + r0 * 2 + 1] = l0s[r];
      int r1 = r0 + 16;
      ml[slot * 256 + r1 * 2 + 0] = m1s[r];
      ml[slot * 256 + r1 * 2 + 1] = l1s[r];
    }
  }
}

// ---------------- combine partials -> normalized O (bf16) ----------------
__global__ __launch_bounds__(512) void k_comb3(const u16* __restrict__ opA, const u16* __restrict__ opB,
                                               const float* __restrict__ ml, u16* __restrict__ Ob,
                                               int lgGq, int SPLIT) {
  const int qb = blockIdx.x;
  const int Gq = 1 << lgGq;
  const int a = qb >> lgGq, b = qb & (Gq - 1);
  const int nch = a + 1;
  const int base = (a + 1) * ((Gq >> 1) * a + b);
  const int t = threadIdx.x;
  const int l = t & 63, w = t >> 6;
  const int l16 = l & 15, g = l >> 4;
  float mv[8][4], lv[8][4], wgt[8][4];
  float M[4] = {-3.0e38f, -3.0e38f, -3.0e38f, -3.0e38f};
#pragma unroll 8
  for (int c = 0; c < 8; c++)
    if (c < nch)
#pragma unroll
      for (int r = 0; r < 4; r++) {
        int rowl = 16 * w + 4 * g + r;
        mv[c][r] = ml[(base + c) * 256 + rowl * 2 + 0];
        lv[c][r] = ml[(base + c) * 256 + rowl * 2 + 1];
        M[r] = fmaxf(M[r], mv[c][r]);
      }
  float L[4] = {0.f, 0.f, 0.f, 0.f};
#pragma unroll 8
  for (int c = 0; c < 8; c++)
    if (c < nch)
#pragma unroll
      for (int r = 0; r < 4; r++) {
        wgt[c][r] = __expf(mv[c][r] - M[r]);
        L[r] += wgt[c][r] * lv[c][r];
      }
  float inv[4];
#pragma unroll
  for (int r = 0; r < 4; r++) inv[r] = 1.0f / L[r];
#pragma unroll
  for (int db2 = 0; db2 < 16; db2++) {
    float o[8] = {};
#pragma unroll 8
    for (int c = 0; c < 8; c++)
      if (c < nch) {
        int slot = base + c;
        const uint4* src = (slot < SPLIT) ? (const uint4*)(opA + (size_t)slot * 65536)
                                          : (const uint4*)(opB + (size_t)(slot - SPLIT) * 65536);
        uint4 v = src[w * 1024 + db2 * 64 + l];
        union { uint4 u; u16 h[8]; } un; un.u = v;
#pragma unroll
        for (int j = 0; j < 8; j++) o[j] += wgt[c][j & 3] * bf2f(un.h[j]);
      }
#pragma unroll
    for (int j = 0; j < 8; j++) {
      int row = qb * 128 + 16 * w + 4 * g + (j & 3);
      int col = 32 * db2 + 16 * (j >> 2) + l16;
      Ob[(size_t)row * 512 + col] = f2bf(o[j] * inv[j & 3]);
    }
  }
}

extern "C" void kernel_launch(void* const* d_in, const int* in_sizes, int n_in,
                              void* d_out, int out_size, void* d_ws, size_t ws_size,
                              hipStream_t stream) {
  const float* x     = (const float*)d_in[0];
  const float* w_qkv = (const float*)d_in[1];
  const float* b_qkv = (const float*)d_in[2];
  const float* w_out = (const float*)d_in[3];
  const float* b_out = (const float*)d_in[4];
  float* out = (float*)d_out;
  char* ws = (char*)d_ws;
  // base layout
  u16* xb    = (u16*)(ws);               // [8192][1024] bf16 (dead after gemm1 -> opA)
  u16* wqkvT = (u16*)(ws + 16777216);    // [1536][1024] bf16 (dead after gemm1 -> opA)
  u16* woutT = (u16*)(ws + 19922944);    // [1024][512]  bf16
  u16* qkv   = (u16*)(ws + 20971520);    // [8192][1536] bf16
  u16* vt    = (u16*)(ws + 46137344);    // [512][8192]  bf16
  u16* Ob    = (u16*)(ws + 54525952);    // [8192][512]  bf16 (ends 62914560)

  // partials: 288 slots x 128 KB. A: slots [0,152) over dead xb+wqkvT (152*131072 = 19922944);
  // B: slots [152,288) at 62914560 (ends 80740352). ml at 80740352 (288*256*4 = 294912).
  const int SPLIT = 152;
  u16* opA = (u16*)ws;
  u16* opB = (u16*)(ws + 62914560);
  float* mlp = (float*)(ws + 80740352);
  const int lgGq = 3, maxc = 8;

  k_cvt<<<4096, 256, 0, stream>>>(x, xb, 8192 * 1024);
  k_tcvt<<<dim3(24, 16), 256, 0, stream>>>(w_qkv, wqkvT, 1024, 1536);
  k_tcvt<<<dim3(16, 8), 256, 0, stream>>>(w_out, woutT, 512, 1024);
  k_gemm<<<dim3(12, 64), 256, 0, stream>>>(xb, wqkvT, b_qkv, qkv, nullptr, 8192, 1536, 1024);
  k_tv<<<dim3(8, 128), 256, 0, stream>>>(qkv, vt);
  k_flash7<<<dim3(maxc, 64), 256, 0, stream>>>(qkv, vt, opA, opB, mlp, lgGq, SPLIT);
  k_comb3<<<64, 512, 0, stream>>>(opA, opB, mlp, Ob, lgGq, SPLIT);
  k_gemm<<<dim3(8, 64), 256, 0, stream>>>(Ob, woutT, b_out, nullptr, out, 8192, 1024, 512);
}

// Round 8
// 461.347 us; speedup vs baseline: 4.4175x; 4.4175x over previous
//
#include <hip/hip_runtime.h>

typedef unsigned short u16;
typedef unsigned int u32;
typedef __attribute__((ext_vector_type(8))) short bf16x8;
typedef __attribute__((ext_vector_type(4))) float f32x4;

__device__ __forceinline__ u16 f2bf(float f) {
  u32 u = __float_as_uint(f);
  u += 0x7fffu + ((u >> 16) & 1u);
  return (u16)(u >> 16);
}
__device__ __forceinline__ float bf2f(short h) {
  return __uint_as_float(((u32)(u16)h) << 16);
}

// ---------------- convert x: f32 -> bf16 (straight) ----------------
__global__ __launch_bounds__(256) void k_cvt(const float* __restrict__ in, u16* __restrict__ out, int n) {
  int idx = (blockIdx.x * 256 + threadIdx.x) * 8;
  if (idx >= n) return;
  float4 a = *(const float4*)&in[idx];
  float4 b = *(const float4*)&in[idx + 4];
  union { u16 h[8]; uint4 v; } t;
  t.h[0] = f2bf(a.x); t.h[1] = f2bf(a.y); t.h[2] = f2bf(a.z); t.h[3] = f2bf(a.w);
  t.h[4] = f2bf(b.x); t.h[5] = f2bf(b.y); t.h[6] = f2bf(b.z); t.h[7] = f2bf(b.w);
  *(uint4*)&out[idx] = t.v;
}

// ---------------- transpose+convert: out[c][r] = bf16(in[r][c]) ----------------
__global__ __launch_bounds__(256) void k_tcvt(const float* __restrict__ in, u16* __restrict__ out, int R, int C) {
  __shared__ u16 T[64 * 72];
  int t = threadIdx.x;
  int r0 = blockIdx.y * 64, c0 = blockIdx.x * 64;
  for (int i = 0; i < 4; i++) {
    int cc = i * 256 + t; int r = cc >> 4; int s = cc & 15;
    float4 v = *(const float4*)&in[(size_t)(r0 + r) * C + c0 + s * 4];
    T[r * 72 + s * 4 + 0] = f2bf(v.x);
    T[r * 72 + s * 4 + 1] = f2bf(v.y);
    T[r * 72 + s * 4 + 2] = f2bf(v.z);
    T[r * 72 + s * 4 + 3] = f2bf(v.w);
  }
  __syncthreads();
  for (int i = 0; i < 2; i++) {
    int cc = i * 256 + t; int c = cc >> 3; int s2 = cc & 7;
    union { u16 h[8]; uint4 v; } tmp;
    for (int e = 0; e < 8; e++) tmp.h[e] = T[(s2 * 8 + e) * 72 + c];
    *(uint4*)&out[(size_t)(c0 + c) * R + r0 + s2 * 8] = tmp.v;
  }
}

// ---------------- transpose v-part of qkv into Vt[512][8192] ----------------
__global__ __launch_bounds__(256) void k_tv(const u16* __restrict__ qkv, u16* __restrict__ vt) {
  __shared__ u16 T[64 * 72];
  int t = threadIdx.x;
  int r0 = blockIdx.y * 64, d0 = blockIdx.x * 64;
  for (int i = 0; i < 2; i++) {
    int cc = i * 256 + t; int r = cc >> 3; int s = cc & 7;
    *(uint4*)&T[r * 72 + s * 8] = *(const uint4*)&qkv[(size_t)(r0 + r) * 1536 + 1024 + d0 + s * 8];
  }
  __syncthreads();
  for (int i = 0; i < 2; i++) {
    int cc = i * 256 + t; int d = cc >> 3; int s2 = cc & 7;
    union { u16 h[8]; uint4 v; } tmp;
    for (int e = 0; e < 8; e++) tmp.h[e] = T[(s2 * 8 + e) * 72 + d];
    *(uint4*)&vt[(size_t)(d0 + d) * 8192 + r0 + s2 * 8] = tmp.v;
  }
}

// ---------------- GEMM (m97 structure) ----------------
__global__ __launch_bounds__(256) void k_gemm(const u16* __restrict__ A, const u16* __restrict__ Bt,
                                              const float* __restrict__ bias,
                                              u16* __restrict__ Cb, float* __restrict__ Cf,
                                              int M, int N, int K) {
  __shared__ u16 As[128 * 64];
  __shared__ u16 Bs[128 * 64];
  const int t = threadIdx.x;
  const int l = t & 63, w = t >> 6;
  const int l16 = l & 15, g = l >> 4;
  const int m0 = blockIdx.y * 128, n0 = blockIdx.x * 128;
  const int wr = (w >> 1) * 64, wc = (w & 1) * 64;
  f32x4 acc[4][4] = {};
  for (int kk = 0; kk < K; kk += 64) {
    __syncthreads();
#pragma unroll
    for (int i = 0; i < 4; i++) {
      int c = i * 256 + t;
      int r = c >> 3, g2 = c & 7;
      int sg = g2 ^ (r & 7);
      __builtin_amdgcn_global_load_lds(
          (const __attribute__((address_space(1))) u32*)(A + (size_t)(m0 + r) * K + kk + sg * 8),
          (__attribute__((address_space(3))) u32*)&As[c * 8], 16, 0, 0);
      __builtin_amdgcn_global_load_lds(
          (const __attribute__((address_space(1))) u32*)(Bt + (size_t)(n0 + r) * K + kk + sg * 8),
          (__attribute__((address_space(3))) u32*)&Bs[c * 8], 16, 0, 0);
    }
    __syncthreads();
#pragma unroll
    for (int kh = 0; kh < 2; kh++) {
      bf16x8 a[4];
#pragma unroll
      for (int mi = 0; mi < 4; mi++) {
        int row = wr + 16 * mi + l16;
        int s = (kh * 4 + g) ^ (row & 7);
        a[mi] = *(const bf16x8*)&As[row * 64 + s * 8];
      }
#pragma unroll
      for (int ni = 0; ni < 4; ni++) {
        int row = wc + 16 * ni + l16;
        int s = (kh * 4 + g) ^ (row & 7);
        bf16x8 b = *(const bf16x8*)&Bs[row * 64 + s * 8];
#pragma unroll
        for (int mi = 0; mi < 4; mi++)
          acc[mi][ni] = __builtin_amdgcn_mfma_f32_16x16x32_bf16(a[mi], b, acc[mi][ni], 0, 0, 0);
      }
    }
  }
#pragma unroll
  for (int ni = 0; ni < 4; ni++) {
    int col = n0 + wc + 16 * ni + l16;
    float bv = bias[col];
#pragma unroll
    for (int mi = 0; mi < 4; mi++) {
      int row0 = m0 + wr + 16 * mi + 4 * g;
#pragma unroll
      for (int r = 0; r < 4; r++) {
        float v = acc[mi][ni][r] + bv;
        if (Cf) Cf[(size_t)(row0 + r) * N + col] = v;
        else    Cb[(size_t)(row0 + r) * N + col] = f2bf(v);
      }
    }
  }
}

// ---------------- flash v8: BQ=128, 8 waves x 16q, single-buffered 32-tok KV, 2 blocks/CU ----------------
// Chunk CT = 4*Gq 32-tok tiles. nch(qb) = (qb>>lgGq)+1; slot = (a+1)*((Gq/2)*a+b)+c.
// lgGq=2: 544 slots (512-tok chunks); lgGq=3 fallback: 288 slots.
// Op layout per slot (65536 u16): [w(0..7)][db2(0..15)][lane][8], rows 16w+4g+r, col 32db2+16(j>>2)+l16.
// Regions: A slots [0,152), B [152,288), C [288,...) in d_out.
__global__ __launch_bounds__(512, 2) void k_flash8(const u16* __restrict__ qkv, const u16* __restrict__ vt,
                                                   u16* __restrict__ opA, u16* __restrict__ opB,
                                                   u16* __restrict__ opC, float* __restrict__ ml, int lgGq) {
  __shared__ u16 Ks[32 * 512];    // [kv][d], 16B units XOR-swizzled by kv-row (single buffer)
  __shared__ u16 Vs[32 * 512];    // subtiled: unit U = (d>>4)*64 + u*16 + (d&15), u = kv>>3
  __shared__ u16 Ps[8][16 * 40];  // per-wave P strip [16 q][32 kv], stride 40
  const int c = blockIdx.x;
  const int qb = 63 - blockIdx.y;             // long blocks dispatched first
  const int Gq = 1 << lgGq;
  const int a = qb >> lgGq, b = qb & (Gq - 1);
  const int nch = a + 1;
  if (c >= nch) return;
  const int slot = (a + 1) * ((Gq >> 1) * a + b) + c;
  const int CT = Gq << 2;
  const int jlo = c * CT;
  const int jhi = min(jlo + CT, (qb + 1) * 4);
  const int t = threadIdx.x;
  const int l = t & 63, w = t >> 6;
  const int l16 = l & 15, g = l >> 4;
  const int q0 = qb * 128;
  const int wq = q0 + 16 * w;                 // wave's first q row
  const float scale = 0.044194173824159216f;  // 1/sqrt(512)

  // hoist Q A-fragments (64 VGPR)
  bf16x8 qa[16];
#pragma unroll
  for (int ks = 0; ks < 16; ks++)
    qa[ks] = *(const bf16x8*)&qkv[(size_t)(wq + l16) * 1536 + ks * 32 + g * 8];

  f32x4 acc[32] = {};                          // O: col = 16db+l16, row = wq+4g+r
  float m_st[4], l_st[4];
#pragma unroll
  for (int r = 0; r < 4; r++) { m_st[r] = -1.0e30f; l_st[r] = 0.f; }

  for (int jt = jlo; jt < jhi; ++jt) {
    const int tok0 = jt * 32;
    __syncthreads();                           // all waves done reading previous tile
    // ---- stage K (32x512) and V (512x32, subtiled) ----
#pragma unroll
    for (int i = 0; i < 4; i++) {
      int cc = i * 512 + t;                    // 16B unit 0..2047
      int r = cc >> 6, u = cc & 63;
      int su = (u & 56) | ((u & 7) ^ (r & 7));
      __builtin_amdgcn_global_load_lds(
          (const __attribute__((address_space(1))) u32*)(qkv + (size_t)(tok0 + r) * 1536 + 512 + su * 8),
          (__attribute__((address_space(3))) u32*)&Ks[cc * 8], 16, 0, 0);
    }
#pragma unroll
    for (int i = 0; i < 4; i++) {
      int cc = i * 512 + t;                    // unit U: tile=U>>6, u=(U>>4)&3, dl=U&15
      int tile = cc >> 6, u = (cc >> 4) & 3, dl = cc & 15;
      int d = tile * 16 + dl;
      __builtin_amdgcn_global_load_lds(
          (const __attribute__((address_space(1))) u32*)(vt + (size_t)d * 8192 + tok0 + u * 8),
          (__attribute__((address_space(3))) u32*)&Vs[cc * 8], 16, 0, 0);
    }
    __syncthreads();                           // staging complete (vmcnt drained at barrier)

    // ---- QK^T: 16 rows x 32 cols, K=512, 4 independent chains (ks parity) ----
    f32x4 S0a = {0.f,0.f,0.f,0.f}, S0b = {0.f,0.f,0.f,0.f};
    f32x4 S1a = {0.f,0.f,0.f,0.f}, S1b = {0.f,0.f,0.f,0.f};
    __builtin_amdgcn_s_setprio(1);
#pragma unroll
    for (int ks = 0; ks < 16; ks++) {
      int u = 4 * ks + g;
      int su = (u & 56) | ((u & 7) ^ (l16 & 7));
      bf16x8 k0 = *(const bf16x8*)&Ks[l16 * 512 + su * 8];
      bf16x8 k1 = *(const bf16x8*)&Ks[(16 + l16) * 512 + su * 8];
      if (ks & 1) {
        S0b = __builtin_amdgcn_mfma_f32_16x16x32_bf16(qa[ks], k0, S0b, 0, 0, 0);
        S1b = __builtin_amdgcn_mfma_f32_16x16x32_bf16(qa[ks], k1, S1b, 0, 0, 0);
      } else {
        S0a = __builtin_amdgcn_mfma_f32_16x16x32_bf16(qa[ks], k0, S0a, 0, 0, 0);
        S1a = __builtin_amdgcn_mfma_f32_16x16x32_bf16(qa[ks], k1, S1a, 0, 0, 0);
      }
    }
    __builtin_amdgcn_s_setprio(0);
    f32x4 S0, S1;
#pragma unroll
    for (int r = 0; r < 4; r++) { S0[r] = (S0a[r] + S0b[r]) * scale; S1[r] = (S1a[r] + S1b[r]) * scale; }
    // ---- causal mask (wave-uniform skip when tile fully visible) ----
    if (tok0 + 31 > wq) {
      const int kv0 = tok0 + l16, kv1 = tok0 + 16 + l16;
      const int qp = wq + 4 * g;
#pragma unroll
      for (int r = 0; r < 4; r++) {
        if (kv0 > qp + r) S0[r] = -1e10f;
        if (kv1 > qp + r) S1[r] = -1e10f;
      }
    }
    // ---- wave-local online softmax with defer-max (THR=6) ----
    float pm[4];
#pragma unroll
    for (int r = 0; r < 4; r++) {
      float v = fmaxf(S0[r], S1[r]);
#pragma unroll
      for (int off = 1; off < 16; off <<= 1) v = fmaxf(v, __shfl_xor(v, off));
      pm[r] = v;
    }
    float sc[4] = {1.f, 1.f, 1.f, 1.f};
    int need = (pm[0] > m_st[0] + 6.f) | (pm[1] > m_st[1] + 6.f) |
               (pm[2] > m_st[2] + 6.f) | (pm[3] > m_st[3] + 6.f);
    if (__any(need)) {
#pragma unroll
      for (int r = 0; r < 4; r++) {
        float mn = fmaxf(m_st[r], pm[r]);
        sc[r] = __expf(m_st[r] - mn);
        m_st[r] = mn;
      }
#pragma unroll
      for (int db = 0; db < 32; db++)
#pragma unroll
        for (int r = 0; r < 4; r++) acc[db][r] *= sc[r];
    }
#pragma unroll
    for (int r = 0; r < 4; r++) {
      float p0 = __expf(S0[r] - m_st[r]);
      float p1 = __expf(S1[r] - m_st[r]);
      Ps[w][(4 * g + r) * 40 + l16] = f2bf(p0);
      Ps[w][(4 * g + r) * 40 + 16 + l16] = f2bf(p1);
      float ps = p0 + p1;
#pragma unroll
      for (int off = 1; off < 16; off <<= 1) ps += __shfl_xor(ps, off);
      l_st[r] = l_st[r] * sc[r] + ps;
    }
    // ---- PV: O[16x512] += P[16x32] @ V[32x512]; V reads conflict-free (contiguous 1KB/instr) ----
    bf16x8 pa = *(const bf16x8*)&Ps[w][l16 * 40 + g * 8];
    __builtin_amdgcn_s_setprio(1);
#pragma unroll
    for (int db = 0; db < 32; db++) {
      bf16x8 vb = *(const bf16x8*)&Vs[db * 512 + g * 128 + l16 * 8];
      acc[db] = __builtin_amdgcn_mfma_f32_16x16x32_bf16(pa, vb, acc[db], 0, 0, 0);
    }
    __builtin_amdgcn_s_setprio(0);
  }

  // ---- epilogue: vectorized unnormalized partials + (m,l) ----
  u16* op = slot < 152 ? opA + (size_t)slot * 65536
          : slot < 288 ? opB + (size_t)(slot - 152) * 65536
                       : opC + (size_t)(slot - 288) * 65536;
  uint4* opw = (uint4*)op;
#pragma unroll
  for (int db2 = 0; db2 < 16; db2++) {
    union { u16 h[8]; uint4 v; } pk;
#pragma unroll
    for (int j = 0; j < 8; j++) pk.h[j] = f2bf(acc[2 * db2 + (j >> 2)][j & 3]);
    opw[w * 1024 + db2 * 64 + l] = pk.v;
  }
  if (l16 == 0) {
#pragma unroll
    for (int r = 0; r < 4; r++) {
      int rowl = 16 * w + 4 * g + r;
      ml[slot * 256 + rowl * 2 + 0] = m_st[r];
      ml[slot * 256 + rowl * 2 + 1] = l_st[r];
    }
  }
}

// ---------------- combine partials -> normalized O (bf16); nch <= 16 ----------------
__global__ __launch_bounds__(512) void k_comb5(const u16* __restrict__ opA, const u16* __restrict__ opB,
                                               const u16* __restrict__ opC, const float* __restrict__ ml,
                                               u16* __restrict__ Ob, int lgGq) {
  __shared__ float wgtS[16][128];
  const int qb = blockIdx.x;
  const int Gq = 1 << lgGq;
  const int a = qb >> lgGq, b = qb & (Gq - 1);
  const int nch = a + 1;
  const int base = (a + 1) * ((Gq >> 1) * a + b);
  const int t = threadIdx.x;
  if (t < 128) {
    float M = -3.0e38f;
    for (int c2 = 0; c2 < nch; c2++) M = fmaxf(M, ml[(base + c2) * 256 + t * 2]);
    float L = 0.f;
    for (int c2 = 0; c2 < nch; c2++) {
      float e = __expf(ml[(base + c2) * 256 + t * 2] - M);
      L += e * ml[(base + c2) * 256 + t * 2 + 1];
      wgtS[c2][t] = e;
    }
    float inv = 1.0f / L;
    for (int c2 = 0; c2 < nch; c2++) wgtS[c2][t] *= inv;
  }
  __syncthreads();
  const int l = t & 63, w = t >> 6;
  const int l16 = l & 15, g = l >> 4;
#pragma unroll 4
  for (int db2 = 0; db2 < 16; db2++) {
    float o[8] = {};
    for (int c2 = 0; c2 < nch; c2++) {
      int slot = base + c2;
      const uint4* src = slot < 152 ? (const uint4*)(opA + (size_t)slot * 65536)
                       : slot < 288 ? (const uint4*)(opB + (size_t)(slot - 152) * 65536)
                                    : (const uint4*)(opC + (size_t)(slot - 288) * 65536);
      uint4 v = src[w * 1024 + db2 * 64 + l];
      union { uint4 u; u16 h[8]; } un; un.u = v;
#pragma unroll
      for (int j = 0; j < 8; j++) o[j] += wgtS[c2][16 * w + 4 * g + (j & 3)] * bf2f(un.h[j]);
    }
#pragma unroll
    for (int j = 0; j < 8; j++) {
      int row = qb * 128 + 16 * w + 4 * g + (j & 3);
      int col = 32 * db2 + 16 * (j >> 2) + l16;
      Ob[(size_t)row * 512 + col] = f2bf(o[j]);
    }
  }
}

extern "C" void kernel_launch(void* const* d_in, const int* in_sizes, int n_in,
                              void* d_out, int out_size, void* d_ws, size_t ws_size,
                              hipStream_t stream) {
  const float* x     = (const float*)d_in[0];
  const float* w_qkv = (const float*)d_in[1];
  const float* b_qkv = (const float*)d_in[2];
  const float* w_out = (const float*)d_in[3];
  const float* b_out = (const float*)d_in[4];
  float* out = (float*)d_out;
  char* ws = (char*)d_ws;
  // base layout
  u16* xb    = (u16*)(ws);               // [8192][1024] bf16 (dead after gemm1 -> opA)
  u16* wqkvT = (u16*)(ws + 16777216);    // [1536][1024] bf16 (dead after gemm1 -> opA)
  u16* woutT = (u16*)(ws + 19922944);    // [1024][512]  bf16
  u16* qkv   = (u16*)(ws + 20971520);    // [8192][1536] bf16
  u16* vt    = (u16*)(ws + 46137344);    // [512][8192]  bf16
  u16* Ob    = (u16*)(ws + 54525952);    // [8192][512]  bf16 (ends 62914560)

  // partials: slots x 128 KB. A: [0, 19922944) = 152 slots (xb+wqkvT dead after gemm1);
  // B: [62914560, 80740352) = 136 slots; C: d_out (33554432 B = exactly 256 slots).
  // ml at 80740352: lgGq=2 needs 557056 (-> 81297408); lgGq=3 needs 294912 (-> 81035264, proven).
  u16* opA = (u16*)ws;
  u16* opB = (u16*)(ws + 62914560);
  u16* opC = (u16*)d_out;
  float* mlp = (float*)(ws + 80740352);
  const int lgGq = (ws_size >= (size_t)81297408) ? 2 : 3;   // 544 slots primary, 288 fallback
  const int maxc = (lgGq == 2) ? 16 : 8;

  k_cvt<<<4096, 256, 0, stream>>>(x, xb, 8192 * 1024);
  k_tcvt<<<dim3(24, 16), 256, 0, stream>>>(w_qkv, wqkvT, 1024, 1536);
  k_tcvt<<<dim3(16, 8), 256, 0, stream>>>(w_out, woutT, 512, 1024);
  k_gemm<<<dim3(12, 64), 256, 0, stream>>>(xb, wqkvT, b_qkv, qkv, nullptr, 8192, 1536, 1024);
  k_tv<<<dim3(8, 128), 256, 0, stream>>>(qkv, vt);
  k_flash8<<<dim3(maxc, 64), 512, 0, stream>>>(qkv, vt, opA, opB, opC, mlp, lgGq);
  k_comb5<<<64, 512, 0, stream>>>(opA, opB, opC, mlp, Ob, lgGq);
  k_gemm<<<dim3(8, 64), 256, 0, stream>>>(Ob, woutT, b_out, nullptr, out, 8192, 1024, 512);
}

// Round 9
// 458.727 us; speedup vs baseline: 4.4428x; 1.0057x over previous
//
#include <hip/hip_runtime.h>

typedef unsigned short u16;
typedef unsigned int u32;
typedef __attribute__((ext_vector_type(8))) short bf16x8;
typedef __attribute__((ext_vector_type(4))) float f32x4;

__device__ __forceinline__ u16 f2bf(float f) {
  u32 u = __float_as_uint(f);
  u += 0x7fffu + ((u >> 16) & 1u);
  return (u16)(u >> 16);
}
__device__ __forceinline__ float bf2f(short h) {
  return __uint_as_float(((u32)(u16)h) << 16);
}

// ---------------- convert x: f32 -> bf16 (straight) ----------------
__global__ __launch_bounds__(256) void k_cvt(const float* __restrict__ in, u16* __restrict__ out, int n) {
  int idx = (blockIdx.x * 256 + threadIdx.x) * 8;
  if (idx >= n) return;
  float4 a = *(const float4*)&in[idx];
  float4 b = *(const float4*)&in[idx + 4];
  union { u16 h[8]; uint4 v; } t;
  t.h[0] = f2bf(a.x); t.h[1] = f2bf(a.y); t.h[2] = f2bf(a.z); t.h[3] = f2bf(a.w);
  t.h[4] = f2bf(b.x); t.h[5] = f2bf(b.y); t.h[6] = f2bf(b.z); t.h[7] = f2bf(b.w);
  *(uint4*)&out[idx] = t.v;
}

// ---------------- transpose+convert: out[c][r] = bf16(in[r][c]) ----------------
__global__ __launch_bounds__(256) void k_tcvt(const float* __restrict__ in, u16* __restrict__ out, int R, int C) {
  __shared__ u16 T[64 * 72];
  int t = threadIdx.x;
  int r0 = blockIdx.y * 64, c0 = blockIdx.x * 64;
  for (int i = 0; i < 4; i++) {
    int cc = i * 256 + t; int r = cc >> 4; int s = cc & 15;
    float4 v = *(const float4*)&in[(size_t)(r0 + r) * C + c0 + s * 4];
    T[r * 72 + s * 4 + 0] = f2bf(v.x);
    T[r * 72 + s * 4 + 1] = f2bf(v.y);
    T[r * 72 + s * 4 + 2] = f2bf(v.z);
    T[r * 72 + s * 4 + 3] = f2bf(v.w);
  }
  __syncthreads();
  for (int i = 0; i < 2; i++) {
    int cc = i * 256 + t; int c = cc >> 3; int s2 = cc & 7;
    union { u16 h[8]; uint4 v; } tmp;
    for (int e = 0; e < 8; e++) tmp.h[e] = T[(s2 * 8 + e) * 72 + c];
    *(uint4*)&out[(size_t)(c0 + c) * R + r0 + s2 * 8] = tmp.v;
  }
}

// ---------------- transpose v-part of qkv into Vt[512][8192] ----------------
__global__ __launch_bounds__(256) void k_tv(const u16* __restrict__ qkv, u16* __restrict__ vt) {
  __shared__ u16 T[64 * 72];
  int t = threadIdx.x;
  int r0 = blockIdx.y * 64, d0 = blockIdx.x * 64;
  for (int i = 0; i < 2; i++) {
    int cc = i * 256 + t; int r = cc >> 3; int s = cc & 7;
    *(uint4*)&T[r * 72 + s * 8] = *(const uint4*)&qkv[(size_t)(r0 + r) * 1536 + 1024 + d0 + s * 8];
  }
  __syncthreads();
  for (int i = 0; i < 2; i++) {
    int cc = i * 256 + t; int d = cc >> 3; int s2 = cc & 7;
    union { u16 h[8]; uint4 v; } tmp;
    for (int e = 0; e < 8; e++) tmp.h[e] = T[(s2 * 8 + e) * 72 + d];
    *(uint4*)&vt[(size_t)(d0 + d) * 8192 + r0 + s2 * 8] = tmp.v;
  }
}

// ---------------- GEMM (m97 structure) ----------------
__global__ __launch_bounds__(256) void k_gemm(const u16* __restrict__ A, const u16* __restrict__ Bt,
                                              const float* __restrict__ bias,
                                              u16* __restrict__ Cb, float* __restrict__ Cf,
                                              int M, int N, int K) {
  __shared__ u16 As[128 * 64];
  __shared__ u16 Bs[128 * 64];
  const int t = threadIdx.x;
  const int l = t & 63, w = t >> 6;
  const int l16 = l & 15, g = l >> 4;
  const int m0 = blockIdx.y * 128, n0 = blockIdx.x * 128;
  const int wr = (w >> 1) * 64, wc = (w & 1) * 64;
  f32x4 acc[4][4] = {};
  for (int kk = 0; kk < K; kk += 64) {
    __syncthreads();
#pragma unroll
    for (int i = 0; i < 4; i++) {
      int c = i * 256 + t;
      int r = c >> 3, g2 = c & 7;
      int sg = g2 ^ (r & 7);
      __builtin_amdgcn_global_load_lds(
          (const __attribute__((address_space(1))) u32*)(A + (size_t)(m0 + r) * K + kk + sg * 8),
          (__attribute__((address_space(3))) u32*)&As[c * 8], 16, 0, 0);
      __builtin_amdgcn_global_load_lds(
          (const __attribute__((address_space(1))) u32*)(Bt + (size_t)(n0 + r) * K + kk + sg * 8),
          (__attribute__((address_space(3))) u32*)&Bs[c * 8], 16, 0, 0);
    }
    __syncthreads();
#pragma unroll
    for (int kh = 0; kh < 2; kh++) {
      bf16x8 a[4];
#pragma unroll
      for (int mi = 0; mi < 4; mi++) {
        int row = wr + 16 * mi + l16;
        int s = (kh * 4 + g) ^ (row & 7);
        a[mi] = *(const bf16x8*)&As[row * 64 + s * 8];
      }
#pragma unroll
      for (int ni = 0; ni < 4; ni++) {
        int row = wc + 16 * ni + l16;
        int s = (kh * 4 + g) ^ (row & 7);
        bf16x8 b = *(const bf16x8*)&Bs[row * 64 + s * 8];
#pragma unroll
        for (int mi = 0; mi < 4; mi++)
          acc[mi][ni] = __builtin_amdgcn_mfma_f32_16x16x32_bf16(a[mi], b, acc[mi][ni], 0, 0, 0);
      }
    }
  }
#pragma unroll
  for (int ni = 0; ni < 4; ni++) {
    int col = n0 + wc + 16 * ni + l16;
    float bv = bias[col];
#pragma unroll
    for (int mi = 0; mi < 4; mi++) {
      int row0 = m0 + wr + 16 * mi + 4 * g;
#pragma unroll
      for (int r = 0; r < 4; r++) {
        float v = acc[mi][ni][r] + bv;
        if (Cf) Cf[(size_t)(row0 + r) * N + col] = v;
        else    Cb[(size_t)(row0 + r) * N + col] = f2bf(v);
      }
    }
  }
}

// ---------------- flash v9: v8 + XCD-pinned KV chunks ----------------
// Chunk CT = 4*Gq 32-tok tiles. nch(qb) = (qb>>lgGq)+1; slot = (a+1)*((Gq/2)*a+b)+c.
// lgGq=2 (primary): 544 slots, 512-tok chunks, maxc=16.
// XCD pinning: with gridDim.x=16 (multiple of 8), XCD = flat%8 = blockIdx.x%8.
// Remap c = cx<8 ? cx : 23-cx  => chunk c always lands on XCD x(c)= (c<8 ? c : 15-c);
// chunk pair (x, 15-x) per XCD gives a PERFECTLY balanced 68 blocks/XCD, and each
// 1 MB chunk slice is fetched from L3 once, then served from that XCD's L2.
__global__ __launch_bounds__(512, 2) void k_flash9(const u16* __restrict__ qkv, const u16* __restrict__ vt,
                                                   u16* __restrict__ opA, u16* __restrict__ opB,
                                                   u16* __restrict__ opC, float* __restrict__ ml, int lgGq) {
  __shared__ u16 Ks[32 * 512];    // [kv][d], 16B units XOR-swizzled by kv-row (single buffer)
  __shared__ u16 Vs[32 * 512];    // subtiled: unit U = (d>>4)*64 + u*16 + (d&15), u = kv>>3
  __shared__ u16 Ps[8][16 * 40];  // per-wave P strip [16 q][32 kv], stride 40
  const int cx = blockIdx.x;
  const int c = (lgGq == 2 && cx >= 8) ? 23 - cx : cx;   // XCD-pinning remap (bijective 0..15)
  const int qb = 63 - blockIdx.y;             // long blocks dispatched first
  const int Gq = 1 << lgGq;
  const int a = qb >> lgGq, b = qb & (Gq - 1);
  const int nch = a + 1;
  if (c >= nch) return;
  const int slot = (a + 1) * ((Gq >> 1) * a + b) + c;
  const int CT = Gq << 2;
  const int jlo = c * CT;
  const int jhi = min(jlo + CT, (qb + 1) * 4);
  const int t = threadIdx.x;
  const int l = t & 63, w = t >> 6;
  const int l16 = l & 15, g = l >> 4;
  const int q0 = qb * 128;
  const int wq = q0 + 16 * w;                 // wave's first q row
  const float scale = 0.044194173824159216f;  // 1/sqrt(512)

  // hoist Q A-fragments (64 VGPR)
  bf16x8 qa[16];
#pragma unroll
  for (int ks = 0; ks < 16; ks++)
    qa[ks] = *(const bf16x8*)&qkv[(size_t)(wq + l16) * 1536 + ks * 32 + g * 8];

  f32x4 acc[32] = {};                          // O: col = 16db+l16, row = wq+4g+r
  float m_st[4], l_st[4];
#pragma unroll
  for (int r = 0; r < 4; r++) { m_st[r] = -1.0e30f; l_st[r] = 0.f; }

  for (int jt = jlo; jt < jhi; ++jt) {
    const int tok0 = jt * 32;
    __syncthreads();                           // all waves done reading previous tile
    // ---- stage K (32x512) and V (512x32, subtiled) ----
#pragma unroll
    for (int i = 0; i < 4; i++) {
      int cc = i * 512 + t;                    // 16B unit 0..2047
      int r = cc >> 6, u = cc & 63;
      int su = (u & 56) | ((u & 7) ^ (r & 7));
      __builtin_amdgcn_global_load_lds(
          (const __attribute__((address_space(1))) u32*)(qkv + (size_t)(tok0 + r) * 1536 + 512 + su * 8),
          (__attribute__((address_space(3))) u32*)&Ks[cc * 8], 16, 0, 0);
    }
#pragma unroll
    for (int i = 0; i < 4; i++) {
      int cc = i * 512 + t;                    // unit U: tile=U>>6, u=(U>>4)&3, dl=U&15
      int tile = cc >> 6, u = (cc >> 4) & 3, dl = cc & 15;
      int d = tile * 16 + dl;
      __builtin_amdgcn_global_load_lds(
          (const __attribute__((address_space(1))) u32*)(vt + (size_t)d * 8192 + tok0 + u * 8),
          (__attribute__((address_space(3))) u32*)&Vs[cc * 8], 16, 0, 0);
    }
    __syncthreads();                           // staging complete (vmcnt drained at barrier)

    // ---- QK^T: 16 rows x 32 cols, K=512, 4 independent chains (ks parity) ----
    f32x4 S0a = {0.f,0.f,0.f,0.f}, S0b = {0.f,0.f,0.f,0.f};
    f32x4 S1a = {0.f,0.f,0.f,0.f}, S1b = {0.f,0.f,0.f,0.f};
    __builtin_amdgcn_s_setprio(1);
#pragma unroll
    for (int ks = 0; ks < 16; ks++) {
      int u = 4 * ks + g;
      int su = (u & 56) | ((u & 7) ^ (l16 & 7));
      bf16x8 k0 = *(const bf16x8*)&Ks[l16 * 512 + su * 8];
      bf16x8 k1 = *(const bf16x8*)&Ks[(16 + l16) * 512 + su * 8];
      if (ks & 1) {
        S0b = __builtin_amdgcn_mfma_f32_16x16x32_bf16(qa[ks], k0, S0b, 0, 0, 0);
        S1b = __builtin_amdgcn_mfma_f32_16x16x32_bf16(qa[ks], k1, S1b, 0, 0, 0);
      } else {
        S0a = __builtin_amdgcn_mfma_f32_16x16x32_bf16(qa[ks], k0, S0a, 0, 0, 0);
        S1a = __builtin_amdgcn_mfma_f32_16x16x32_bf16(qa[ks], k1, S1a, 0, 0, 0);
      }
    }
    __builtin_amdgcn_s_setprio(0);
    f32x4 S0, S1;
#pragma unroll
    for (int r = 0; r < 4; r++) { S0[r] = (S0a[r] + S0b[r]) * scale; S1[r] = (S1a[r] + S1b[r]) * scale; }
    // ---- causal mask (wave-uniform skip when tile fully visible) ----
    if (tok0 + 31 > wq) {
      const int kv0 = tok0 + l16, kv1 = tok0 + 16 + l16;
      const int qp = wq + 4 * g;
#pragma unroll
      for (int r = 0; r < 4; r++) {
        if (kv0 > qp + r) S0[r] = -1e10f;
        if (kv1 > qp + r) S1[r] = -1e10f;
      }
    }
    // ---- wave-local online softmax with defer-max (THR=6) ----
    float pm[4];
#pragma unroll
    for (int r = 0; r < 4; r++) {
      float v = fmaxf(S0[r], S1[r]);
#pragma unroll
      for (int off = 1; off < 16; off <<= 1) v = fmaxf(v, __shfl_xor(v, off));
      pm[r] = v;
    }
    float sc[4] = {1.f, 1.f, 1.f, 1.f};
    int need = (pm[0] > m_st[0] + 6.f) | (pm[1] > m_st[1] + 6.f) |
               (pm[2] > m_st[2] + 6.f) | (pm[3] > m_st[3] + 6.f);
    if (__any(need)) {
#pragma unroll
      for (int r = 0; r < 4; r++) {
        float mn = fmaxf(m_st[r], pm[r]);
        sc[r] = __expf(m_st[r] - mn);
        m_st[r] = mn;
      }
#pragma unroll
      for (int db = 0; db < 32; db++)
#pragma unroll
        for (int r = 0; r < 4; r++) acc[db][r] *= sc[r];
    }
#pragma unroll
    for (int r = 0; r < 4; r++) {
      float p0 = __expf(S0[r] - m_st[r]);
      float p1 = __expf(S1[r] - m_st[r]);
      Ps[w][(4 * g + r) * 40 + l16] = f2bf(p0);
      Ps[w][(4 * g + r) * 40 + 16 + l16] = f2bf(p1);
      float ps = p0 + p1;
#pragma unroll
      for (int off = 1; off < 16; off <<= 1) ps += __shfl_xor(ps, off);
      l_st[r] = l_st[r] * sc[r] + ps;
    }
    // ---- PV: O[16x512] += P[16x32] @ V[32x512]; V reads conflict-free ----
    bf16x8 pa = *(const bf16x8*)&Ps[w][l16 * 40 + g * 8];
    __builtin_amdgcn_s_setprio(1);
#pragma unroll
    for (int db = 0; db < 32; db++) {
      bf16x8 vb = *(const bf16x8*)&Vs[db * 512 + g * 128 + l16 * 8];
      acc[db] = __builtin_amdgcn_mfma_f32_16x16x32_bf16(pa, vb, acc[db], 0, 0, 0);
    }
    __builtin_amdgcn_s_setprio(0);
  }

  // ---- epilogue: vectorized unnormalized partials + (m,l) ----
  u16* op = slot < 152 ? opA + (size_t)slot * 65536
          : slot < 288 ? opB + (size_t)(slot - 152) * 65536
                       : opC + (size_t)(slot - 288) * 65536;
  uint4* opw = (uint4*)op;
#pragma unroll
  for (int db2 = 0; db2 < 16; db2++) {
    union { u16 h[8]; uint4 v; } pk;
#pragma unroll
    for (int j = 0; j < 8; j++) pk.h[j] = f2bf(acc[2 * db2 + (j >> 2)][j & 3]);
    opw[w * 1024 + db2 * 64 + l] = pk.v;
  }
  if (l16 == 0) {
#pragma unroll
    for (int r = 0; r < 4; r++) {
      int rowl = 16 * w + 4 * g + r;
      ml[slot * 256 + rowl * 2 + 0] = m_st[r];
      ml[slot * 256 + rowl * 2 + 1] = l_st[r];
    }
  }
}

// ---------------- combine partials -> normalized O (bf16); nch <= 16 ----------------
__global__ __launch_bounds__(512) void k_comb5(const u16* __restrict__ opA, const u16* __restrict__ opB,
                                               const u16* __restrict__ opC, const float* __restrict__ ml,
                                               u16* __restrict__ Ob, int lgGq) {
  __shared__ float wgtS[16][128];
  const int qb = blockIdx.x;
  const int Gq = 1 << lgGq;
  const int a = qb >> lgGq, b = qb & (Gq - 1);
  const int nch = a + 1;
  const int base = (a + 1) * ((Gq >> 1) * a + b);
  const int t = threadIdx.x;
  if (t < 128) {
    float M = -3.0e38f;
    for (int c2 = 0; c2 < nch; c2++) M = fmaxf(M, ml[(base + c2) * 256 + t * 2]);
    float L = 0.f;
    for (int c2 = 0; c2 < nch; c2++) {
      float e = __expf(ml[(base + c2) * 256 + t * 2] - M);
      L += e * ml[(base + c2) * 256 + t * 2 + 1];
      wgtS[c2][t] = e;
    }
    float inv = 1.0f / L;
    for (int c2 = 0; c2 < nch; c2++) wgtS[c2][t] *= inv;
  }
  __syncthreads();
  const int l = t & 63, w = t >> 6;
  const int l16 = l & 15, g = l >> 4;
#pragma unroll 4
  for (int db2 = 0; db2 < 16; db2++) {
    float o[8] = {};
    for (int c2 = 0; c2 < nch; c2++) {
      int slot = base + c2;
      const uint4* src = slot < 152 ? (const uint4*)(opA + (size_t)slot * 65536)
                       : slot < 288 ? (const uint4*)(opB + (size_t)(slot - 152) * 65536)
                                    : (const uint4*)(opC + (size_t)(slot - 288) * 65536);
      uint4 v = src[w * 1024 + db2 * 64 + l];
      union { uint4 u; u16 h[8]; } un; un.u = v;
#pragma unroll
      for (int j = 0; j < 8; j++) o[j] += wgtS[c2][16 * w + 4 * g + (j & 3)] * bf2f(un.h[j]);
    }
#pragma unroll
    for (int j = 0; j < 8; j++) {
      int row = qb * 128 + 16 * w + 4 * g + (j & 3);
      int col = 32 * db2 + 16 * (j >> 2) + l16;
      Ob[(size_t)row * 512 + col] = f2bf(o[j]);
    }
  }
}

extern "C" void kernel_launch(void* const* d_in, const int* in_sizes, int n_in,
                              void* d_out, int out_size, void* d_ws, size_t ws_size,
                              hipStream_t stream) {
  const float* x     = (const float*)d_in[0];
  const float* w_qkv = (const float*)d_in[1];
  const float* b_qkv = (const float*)d_in[2];
  const float* w_out = (const float*)d_in[3];
  const float* b_out = (const float*)d_in[4];
  float* out = (float*)d_out;
  char* ws = (char*)d_ws;
  // base layout
  u16* xb    = (u16*)(ws);               // [8192][1024] bf16 (dead after gemm1 -> opA)
  u16* wqkvT = (u16*)(ws + 16777216);    // [1536][1024] bf16 (dead after gemm1 -> opA)
  u16* woutT = (u16*)(ws + 19922944);    // [1024][512]  bf16
  u16* qkv   = (u16*)(ws + 20971520);    // [8192][1536] bf16
  u16* vt    = (u16*)(ws + 46137344);    // [512][8192]  bf16
  u16* Ob    = (u16*)(ws + 54525952);    // [8192][512]  bf16 (ends 62914560)

  // partials: slots x 128 KB. A: [0, 19922944) = 152 slots (xb+wqkvT dead after gemm1);
  // B: [62914560, 80740352) = 136 slots; C: d_out (33554432 B = 256 slots).
  u16* opA = (u16*)ws;
  u16* opB = (u16*)(ws + 62914560);
  u16* opC = (u16*)d_out;
  float* mlp = (float*)(ws + 80740352);
  const int lgGq = (ws_size >= (size_t)81297408) ? 2 : 3;   // 544 slots primary, 288 fallback
  const int maxc = (lgGq == 2) ? 16 : 8;

  k_cvt<<<4096, 256, 0, stream>>>(x, xb, 8192 * 1024);
  k_tcvt<<<dim3(24, 16), 256, 0, stream>>>(w_qkv, wqkvT, 1024, 1536);
  k_tcvt<<<dim3(16, 8), 256, 0, stream>>>(w_out, woutT, 512, 1024);
  k_gemm<<<dim3(12, 64), 256, 0, stream>>>(xb, wqkvT, b_qkv, qkv, nullptr, 8192, 1536, 1024);
  k_tv<<<dim3(8, 128), 256, 0, stream>>>(qkv, vt);
  k_flash9<<<dim3(maxc, 64), 512, 0, stream>>>(qkv, vt, opA, opB, opC, mlp, lgGq);
  k_comb5<<<64, 512, 0, stream>>>(opA, opB, opC, mlp, Ob, lgGq);
  k_gemm<<<dim3(8, 64), 256, 0, stream>>>(Ob, woutT, b_out, nullptr, out, 8192, 1024, 512);
}

// Round 10
// 380.868 us; speedup vs baseline: 5.3510x; 1.2044x over previous
//
#include <hip/hip_runtime.h>

typedef unsigned short u16;
typedef unsigned int u32;
typedef __attribute__((ext_vector_type(8))) short bf16x8;
typedef __attribute__((ext_vector_type(4))) float f32x4;

__device__ __forceinline__ u16 f2bf(float f) {
  u32 u = __float_as_uint(f);
  u += 0x7fffu + ((u >> 16) & 1u);
  return (u16)(u >> 16);
}
__device__ __forceinline__ float bf2f(short h) {
  return __uint_as_float(((u32)(u16)h) << 16);
}

// ---------------- convert x: f32 -> bf16 (straight) ----------------
__global__ __launch_bounds__(256) void k_cvt(const float* __restrict__ in, u16* __restrict__ out, int n) {
  int idx = (blockIdx.x * 256 + threadIdx.x) * 8;
  if (idx >= n) return;
  float4 a = *(const float4*)&in[idx];
  float4 b = *(const float4*)&in[idx + 4];
  union { u16 h[8]; uint4 v; } t;
  t.h[0] = f2bf(a.x); t.h[1] = f2bf(a.y); t.h[2] = f2bf(a.z); t.h[3] = f2bf(a.w);
  t.h[4] = f2bf(b.x); t.h[5] = f2bf(b.y); t.h[6] = f2bf(b.z); t.h[7] = f2bf(b.w);
  *(uint4*)&out[idx] = t.v;
}

// ---------------- transpose+convert: out[c][r] = bf16(in[r][c]) ----------------
__global__ __launch_bounds__(256) void k_tcvt(const float* __restrict__ in, u16* __restrict__ out, int R, int C) {
  __shared__ u16 T[64 * 72];
  int t = threadIdx.x;
  int r0 = blockIdx.y * 64, c0 = blockIdx.x * 64;
  for (int i = 0; i < 4; i++) {
    int cc = i * 256 + t; int r = cc >> 4; int s = cc & 15;
    float4 v = *(const float4*)&in[(size_t)(r0 + r) * C + c0 + s * 4];
    T[r * 72 + s * 4 + 0] = f2bf(v.x);
    T[r * 72 + s * 4 + 1] = f2bf(v.y);
    T[r * 72 + s * 4 + 2] = f2bf(v.z);
    T[r * 72 + s * 4 + 3] = f2bf(v.w);
  }
  __syncthreads();
  for (int i = 0; i < 2; i++) {
    int cc = i * 256 + t; int c = cc >> 3; int s2 = cc & 7;
    union { u16 h[8]; uint4 v; } tmp;
    for (int e = 0; e < 8; e++) tmp.h[e] = T[(s2 * 8 + e) * 72 + c];
    *(uint4*)&out[(size_t)(c0 + c) * R + r0 + s2 * 8] = tmp.v;
  }
}

// ---------------- transpose v-part of qkv into Vt[512][8192] ----------------
__global__ __launch_bounds__(256) void k_tv(const u16* __restrict__ qkv, u16* __restrict__ vt) {
  __shared__ u16 T[64 * 72];
  int t = threadIdx.x;
  int r0 = blockIdx.y * 64, d0 = blockIdx.x * 64;
  for (int i = 0; i < 2; i++) {
    int cc = i * 256 + t; int r = cc >> 3; int s = cc & 7;
    *(uint4*)&T[r * 72 + s * 8] = *(const uint4*)&qkv[(size_t)(r0 + r) * 1536 + 1024 + d0 + s * 8];
  }
  __syncthreads();
  for (int i = 0; i < 2; i++) {
    int cc = i * 256 + t; int d = cc >> 3; int s2 = cc & 7;
    union { u16 h[8]; uint4 v; } tmp;
    for (int e = 0; e < 8; e++) tmp.h[e] = T[(s2 * 8 + e) * 72 + d];
    *(uint4*)&vt[(size_t)(d0 + d) * 8192 + r0 + s2 * 8] = tmp.v;
  }
}

// ---------------- pack per-tile LDS images: ktile/vtile[jt] = contiguous 32KB each ----------------
// ktile unit cc (16B): r = cc>>6, u = cc&63, su = (u&56)|((u&7)^(r&7));
//   bytes = qkv[(32jt+r)*1536 + 512 + su*8 .. +8)
// vtile unit cc: tile = cc>>6, u = (cc>>4)&3, dl = cc&15, d = 16*tile+dl;
//   bytes = vt[d*8192 + 32jt + u*8 .. +8)
__global__ __launch_bounds__(256) void k_pack(const u16* __restrict__ qkv, const u16* __restrict__ vt,
                                              u16* __restrict__ ktile, u16* __restrict__ vtile) {
  const int jt = blockIdx.x;
  const int t = threadIdx.x;
  const int tok0 = jt * 32;
  uint4* kd = (uint4*)(ktile + (size_t)jt * 16384);
  uint4* vd = (uint4*)(vtile + (size_t)jt * 16384);
#pragma unroll
  for (int i = 0; i < 8; i++) {
    int cc = i * 256 + t;
    int r = cc >> 6, u = cc & 63;
    int su = (u & 56) | ((u & 7) ^ (r & 7));
    kd[cc] = *(const uint4*)&qkv[(size_t)(tok0 + r) * 1536 + 512 + su * 8];
  }
#pragma unroll
  for (int i = 0; i < 8; i++) {
    int cc = i * 256 + t;
    int tile = cc >> 6, u = (cc >> 4) & 3, dl = cc & 15;
    int d = tile * 16 + dl;
    vd[cc] = *(const uint4*)&vt[(size_t)d * 8192 + tok0 + u * 8];
  }
}

// ---------------- GEMM (m97 structure) ----------------
__global__ __launch_bounds__(256) void k_gemm(const u16* __restrict__ A, const u16* __restrict__ Bt,
                                              const float* __restrict__ bias,
                                              u16* __restrict__ Cb, float* __restrict__ Cf,
                                              int M, int N, int K) {
  __shared__ u16 As[128 * 64];
  __shared__ u16 Bs[128 * 64];
  const int t = threadIdx.x;
  const int l = t & 63, w = t >> 6;
  const int l16 = l & 15, g = l >> 4;
  const int m0 = blockIdx.y * 128, n0 = blockIdx.x * 128;
  const int wr = (w >> 1) * 64, wc = (w & 1) * 64;
  f32x4 acc[4][4] = {};
  for (int kk = 0; kk < K; kk += 64) {
    __syncthreads();
#pragma unroll
    for (int i = 0; i < 4; i++) {
      int c = i * 256 + t;
      int r = c >> 3, g2 = c & 7;
      int sg = g2 ^ (r & 7);
      __builtin_amdgcn_global_load_lds(
          (const __attribute__((address_space(1))) u32*)(A + (size_t)(m0 + r) * K + kk + sg * 8),
          (__attribute__((address_space(3))) u32*)&As[c * 8], 16, 0, 0);
      __builtin_amdgcn_global_load_lds(
          (const __attribute__((address_space(1))) u32*)(Bt + (size_t)(n0 + r) * K + kk + sg * 8),
          (__attribute__((address_space(3))) u32*)&Bs[c * 8], 16, 0, 0);
    }
    __syncthreads();
#pragma unroll
    for (int kh = 0; kh < 2; kh++) {
      bf16x8 a[4];
#pragma unroll
      for (int mi = 0; mi < 4; mi++) {
        int row = wr + 16 * mi + l16;
        int s = (kh * 4 + g) ^ (row & 7);
        a[mi] = *(const bf16x8*)&As[row * 64 + s * 8];
      }
#pragma unroll
      for (int ni = 0; ni < 4; ni++) {
        int row = wc + 16 * ni + l16;
        int s = (kh * 4 + g) ^ (row & 7);
        bf16x8 b = *(const bf16x8*)&Bs[row * 64 + s * 8];
#pragma unroll
        for (int mi = 0; mi < 4; mi++)
          acc[mi][ni] = __builtin_amdgcn_mfma_f32_16x16x32_bf16(a[mi], b, acc[mi][ni], 0, 0, 0);
      }
    }
  }
#pragma unroll
  for (int ni = 0; ni < 4; ni++) {
    int col = n0 + wc + 16 * ni + l16;
    float bv = bias[col];
#pragma unroll
    for (int mi = 0; mi < 4; mi++) {
      int row0 = m0 + wr + 16 * mi + 4 * g;
#pragma unroll
      for (int r = 0; r < 4; r++) {
        float v = acc[mi][ni][r] + bv;
        if (Cf) Cf[(size_t)(row0 + r) * N + col] = v;
        else    Cb[(size_t)(row0 + r) * N + col] = f2bf(v);
      }
    }
  }
}

// ---------------- flash v10: v9 compute, staging from pre-packed linear tiles ----------------
__global__ __launch_bounds__(512, 2) void k_flash10(const u16* __restrict__ qkv,
                                                    const u16* __restrict__ ktile, const u16* __restrict__ vtile,
                                                    u16* __restrict__ opA, u16* __restrict__ opB,
                                                    u16* __restrict__ opC, float* __restrict__ ml, int lgGq) {
  __shared__ u16 Ks[32 * 512];    // LDS image == ktile[jt] (swizzle baked in)
  __shared__ u16 Vs[32 * 512];    // LDS image == vtile[jt] (subtiling baked in)
  __shared__ u16 Ps[8][16 * 40];  // per-wave P strip [16 q][32 kv], stride 40
  const int cx = blockIdx.x;
  const int c = (lgGq == 2 && cx >= 8) ? 23 - cx : cx;   // XCD-pinning remap (bijective 0..15)
  const int qb = 63 - blockIdx.y;             // long blocks dispatched first
  const int Gq = 1 << lgGq;
  const int a = qb >> lgGq, b = qb & (Gq - 1);
  const int nch = a + 1;
  if (c >= nch) return;
  const int slot = (a + 1) * ((Gq >> 1) * a + b) + c;
  const int CT = Gq << 2;
  const int jlo = c * CT;
  const int jhi = min(jlo + CT, (qb + 1) * 4);
  const int t = threadIdx.x;
  const int l = t & 63, w = t >> 6;
  const int l16 = l & 15, g = l >> 4;
  const int q0 = qb * 128;
  const int wq = q0 + 16 * w;                 // wave's first q row
  const float scale = 0.044194173824159216f;  // 1/sqrt(512)

  // hoist Q A-fragments (64 VGPR)
  bf16x8 qa[16];
#pragma unroll
  for (int ks = 0; ks < 16; ks++)
    qa[ks] = *(const bf16x8*)&qkv[(size_t)(wq + l16) * 1536 + ks * 32 + g * 8];

  f32x4 acc[32] = {};                          // O: col = 16db+l16, row = wq+4g+r
  float m_st[4], l_st[4];
#pragma unroll
  for (int r = 0; r < 4; r++) { m_st[r] = -1.0e30f; l_st[r] = 0.f; }

  for (int jt = jlo; jt < jhi; ++jt) {
    __syncthreads();                           // all waves done reading previous tile
    // ---- stage K and V: pure linear copy of the pre-packed 32KB images ----
    const u16* ks_src = ktile + (size_t)jt * 16384;
    const u16* vs_src = vtile + (size_t)jt * 16384;
#pragma unroll
    for (int i = 0; i < 4; i++) {
      int cc = i * 512 + t;
      __builtin_amdgcn_global_load_lds(
          (const __attribute__((address_space(1))) u32*)(ks_src + cc * 8),
          (__attribute__((address_space(3))) u32*)&Ks[cc * 8], 16, 0, 0);
    }
#pragma unroll
    for (int i = 0; i < 4; i++) {
      int cc = i * 512 + t;
      __builtin_amdgcn_global_load_lds(
          (const __attribute__((address_space(1))) u32*)(vs_src + cc * 8),
          (__attribute__((address_space(3))) u32*)&Vs[cc * 8], 16, 0, 0);
    }
    __syncthreads();                           // staging complete (vmcnt drained at barrier)

    const int tok0 = jt * 32;
    // ---- QK^T: 16 rows x 32 cols, K=512, 4 independent chains (ks parity) ----
    f32x4 S0a = {0.f,0.f,0.f,0.f}, S0b = {0.f,0.f,0.f,0.f};
    f32x4 S1a = {0.f,0.f,0.f,0.f}, S1b = {0.f,0.f,0.f,0.f};
    __builtin_amdgcn_s_setprio(1);
#pragma unroll
    for (int ks = 0; ks < 16; ks++) {
      int u = 4 * ks + g;
      int su = (u & 56) | ((u & 7) ^ (l16 & 7));
      bf16x8 k0 = *(const bf16x8*)&Ks[l16 * 512 + su * 8];
      bf16x8 k1 = *(const bf16x8*)&Ks[(16 + l16) * 512 + su * 8];
      if (ks & 1) {
        S0b = __builtin_amdgcn_mfma_f32_16x16x32_bf16(qa[ks], k0, S0b, 0, 0, 0);
        S1b = __builtin_amdgcn_mfma_f32_16x16x32_bf16(qa[ks], k1, S1b, 0, 0, 0);
      } else {
        S0a = __builtin_amdgcn_mfma_f32_16x16x32_bf16(qa[ks], k0, S0a, 0, 0, 0);
        S1a = __builtin_amdgcn_mfma_f32_16x16x32_bf16(qa[ks], k1, S1a, 0, 0, 0);
      }
    }
    __builtin_amdgcn_s_setprio(0);
    f32x4 S0, S1;
#pragma unroll
    for (int r = 0; r < 4; r++) { S0[r] = (S0a[r] + S0b[r]) * scale; S1[r] = (S1a[r] + S1b[r]) * scale; }
    // ---- causal mask (wave-uniform skip when tile fully visible) ----
    if (tok0 + 31 > wq) {
      const int kv0 = tok0 + l16, kv1 = tok0 + 16 + l16;
      const int qp = wq + 4 * g;
#pragma unroll
      for (int r = 0; r < 4; r++) {
        if (kv0 > qp + r) S0[r] = -1e10f;
        if (kv1 > qp + r) S1[r] = -1e10f;
      }
    }
    // ---- wave-local online softmax with defer-max (THR=6) ----
    float pm[4];
#pragma unroll
    for (int r = 0; r < 4; r++) {
      float v = fmaxf(S0[r], S1[r]);
#pragma unroll
      for (int off = 1; off < 16; off <<= 1) v = fmaxf(v, __shfl_xor(v, off));
      pm[r] = v;
    }
    float sc[4] = {1.f, 1.f, 1.f, 1.f};
    int need = (pm[0] > m_st[0] + 6.f) | (pm[1] > m_st[1] + 6.f) |
               (pm[2] > m_st[2] + 6.f) | (pm[3] > m_st[3] + 6.f);
    if (__any(need)) {
#pragma unroll
      for (int r = 0; r < 4; r++) {
        float mn = fmaxf(m_st[r], pm[r]);
        sc[r] = __expf(m_st[r] - mn);
        m_st[r] = mn;
      }
#pragma unroll
      for (int db = 0; db < 32; db++)
#pragma unroll
        for (int r = 0; r < 4; r++) acc[db][r] *= sc[r];
    }
#pragma unroll
    for (int r = 0; r < 4; r++) {
      float p0 = __expf(S0[r] - m_st[r]);
      float p1 = __expf(S1[r] - m_st[r]);
      Ps[w][(4 * g + r) * 40 + l16] = f2bf(p0);
      Ps[w][(4 * g + r) * 40 + 16 + l16] = f2bf(p1);
      float ps = p0 + p1;
#pragma unroll
      for (int off = 1; off < 16; off <<= 1) ps += __shfl_xor(ps, off);
      l_st[r] = l_st[r] * sc[r] + ps;
    }
    // ---- PV: O[16x512] += P[16x32] @ V[32x512]; V reads conflict-free ----
    bf16x8 pa = *(const bf16x8*)&Ps[w][l16 * 40 + g * 8];
    __builtin_amdgcn_s_setprio(1);
#pragma unroll
    for (int db = 0; db < 32; db++) {
      bf16x8 vb = *(const bf16x8*)&Vs[db * 512 + g * 128 + l16 * 8];
      acc[db] = __builtin_amdgcn_mfma_f32_16x16x32_bf16(pa, vb, acc[db], 0, 0, 0);
    }
    __builtin_amdgcn_s_setprio(0);
  }

  // ---- epilogue: vectorized unnormalized partials + (m,l) ----
  u16* op = slot < 152 ? opA + (size_t)slot * 65536
          : slot < 288 ? opB + (size_t)(slot - 152) * 65536
                       : opC + (size_t)(slot - 288) * 65536;
  uint4* opw = (uint4*)op;
#pragma unroll
  for (int db2 = 0; db2 < 16; db2++) {
    union { u16 h[8]; uint4 v; } pk;
#pragma unroll
    for (int j = 0; j < 8; j++) pk.h[j] = f2bf(acc[2 * db2 + (j >> 2)][j & 3]);
    opw[w * 1024 + db2 * 64 + l] = pk.v;
  }
  if (l16 == 0) {
#pragma unroll
    for (int r = 0; r < 4; r++) {
      int rowl = 16 * w + 4 * g + r;
      ml[slot * 256 + rowl * 2 + 0] = m_st[r];
      ml[slot * 256 + rowl * 2 + 1] = l_st[r];
    }
  }
}

// ---------------- combine partials -> normalized O (bf16); nch <= 16 ----------------
__global__ __launch_bounds__(512) void k_comb5(const u16* __restrict__ opA, const u16* __restrict__ opB,
                                               const u16* __restrict__ opC, const float* __restrict__ ml,
                                               u16* __restrict__ Ob, int lgGq) {
  __shared__ float wgtS[16][128];
  const int qb = blockIdx.x;
  const int Gq = 1 << lgGq;
  const int a = qb >> lgGq, b = qb & (Gq - 1);
  const int nch = a + 1;
  const int base = (a + 1) * ((Gq >> 1) * a + b);
  const int t = threadIdx.x;
  if (t < 128) {
    float M = -3.0e38f;
    for (int c2 = 0; c2 < nch; c2++) M = fmaxf(M, ml[(base + c2) * 256 + t * 2]);
    float L = 0.f;
    for (int c2 = 0; c2 < nch; c2++) {
      float e = __expf(ml[(base + c2) * 256 + t * 2] - M);
      L += e * ml[(base + c2) * 256 + t * 2 + 1];
      wgtS[c2][t] = e;
    }
    float inv = 1.0f / L;
    for (int c2 = 0; c2 < nch; c2++) wgtS[c2][t] *= inv;
  }
  __syncthreads();
  const int l = t & 63, w = t >> 6;
  const int l16 = l & 15, g = l >> 4;
#pragma unroll 4
  for (int db2 = 0; db2 < 16; db2++) {
    float o[8] = {};
    for (int c2 = 0; c2 < nch; c2++) {
      int slot = base + c2;
      const uint4* src = slot < 152 ? (const uint4*)(opA + (size_t)slot * 65536)
                       : slot < 288 ? (const uint4*)(opB + (size_t)(slot - 152) * 65536)
                                    : (const uint4*)(opC + (size_t)(slot - 288) * 65536);
      uint4 v = src[w * 1024 + db2 * 64 + l];
      union { uint4 u; u16 h[8]; } un; un.u = v;
#pragma unroll
      for (int j = 0; j < 8; j++) o[j] += wgtS[c2][16 * w + 4 * g + (j & 3)] * bf2f(un.h[j]);
    }
#pragma unroll
    for (int j = 0; j < 8; j++) {
      int row = qb * 128 + 16 * w + 4 * g + (j & 3);
      int col = 32 * db2 + 16 * (j >> 2) + l16;
      Ob[(size_t)row * 512 + col] = f2bf(o[j]);
    }
  }
}

extern "C" void kernel_launch(void* const* d_in, const int* in_sizes, int n_in,
                              void* d_out, int out_size, void* d_ws, size_t ws_size,
                              hipStream_t stream) {
  const float* x     = (const float*)d_in[0];
  const float* w_qkv = (const float*)d_in[1];
  const float* b_qkv = (const float*)d_in[2];
  const float* w_out = (const float*)d_in[3];
  const float* b_out = (const float*)d_in[4];
  float* out = (float*)d_out;
  char* ws = (char*)d_ws;
  // base layout
  u16* xb    = (u16*)(ws);               // [8192][1024] bf16 (dead after gemm1 -> opA)
  u16* wqkvT = (u16*)(ws + 16777216);    // [1536][1024] bf16 (dead after gemm1 -> opA)
  u16* woutT = (u16*)(ws + 19922944);    // [1024][512]  bf16
  u16* qkv   = (u16*)(ws + 20971520);    // [8192][1536] bf16 (ends 46137344)
  u16* ktile = (u16*)(ws + 46137344);    // 256 x 32KB packed K tiles (ends 54525952)
  u16* vtile = (u16*)(ws + 54525952);    // 256 x 32KB packed V tiles (ends 62914560)
  u16* vt    = (u16*)(ws + 62914560);    // [512][8192] bf16 TEMP (dead after k_pack -> opB)
  u16* Ob    = (u16*)(ws + 46137344);    // overlays ktile (dead after flash); comb -> gemm2

  // partials: slots x 128 KB. A: [0, 19922944) = 152 slots (xb+wqkvT dead after gemm1);
  // B: [62914560, 80740352) = 136 slots (vt dead after k_pack); C: d_out (256 slots).
  u16* opA = (u16*)ws;
  u16* opB = (u16*)(ws + 62914560);
  u16* opC = (u16*)d_out;
  float* mlp = (float*)(ws + 80740352);
  const int lgGq = (ws_size >= (size_t)81297408) ? 2 : 3;   // 544 slots primary, 288 fallback
  const int maxc = (lgGq == 2) ? 16 : 8;

  k_cvt<<<4096, 256, 0, stream>>>(x, xb, 8192 * 1024);
  k_tcvt<<<dim3(24, 16), 256, 0, stream>>>(w_qkv, wqkvT, 1024, 1536);
  k_tcvt<<<dim3(16, 8), 256, 0, stream>>>(w_out, woutT, 512, 1024);
  k_gemm<<<dim3(12, 64), 256, 0, stream>>>(xb, wqkvT, b_qkv, qkv, nullptr, 8192, 1536, 1024);
  k_tv<<<dim3(8, 128), 256, 0, stream>>>(qkv, vt);
  k_pack<<<256, 256, 0, stream>>>(qkv, vt, ktile, vtile);
  k_flash10<<<dim3(maxc, 64), 512, 0, stream>>>(qkv, ktile, vtile, opA, opB, opC, mlp, lgGq);
  k_comb5<<<64, 512, 0, stream>>>(opA, opB, opC, mlp, Ob, lgGq);
  k_gemm<<<dim3(8, 64), 256, 0, stream>>>(Ob, woutT, b_out, nullptr, out, 8192, 1024, 512);
}